// Round 7
// baseline (175.966 us; speedup 1.0000x reference)
//
#include <hip/hip_runtime.h>
#include <stdint.h>

#define TAGS 10
#define START_TAG 8
#define STOP_TAG 9
#define NEGV (-10000.0f)
#define SENT (-3.0e38f)

// DPP permute within 16-lane rows. ROW_ROR:r = 0x120+r, QUAD_PERM[1,0,3,2]=0xB1.
#define DPP_I(x, ctrl) __builtin_amdgcn_update_dpp(0, (x), (ctrl), 0xF, 0xF, true)
#define AS1C(p) ((const __attribute__((address_space(1))) void*)(p))
#define AS3(p)  ((__attribute__((address_space(3))) void*)(p))

__device__ __forceinline__ float maxf3(float a, float b, float c) {
    return fmaxf(fmaxf(a, b), c);   // folds to v_max3_f32
}

// Fused Viterbi forward + backtrace. 16 lanes/seq (lane n = next-tag n),
// 4 seqs/wave. Feats staged through a 4-slot LDS ring via global_load_lds
// (prefetch distance is structural — no VGPRs hold in-flight data, so the
// scheduler can't shorten it): phase issues loads for t+24, waits vmcnt(8)
// (in-order retirement => exactly "all but the newest 8 loads done"), then
// ds_reads block t+8 into regs for the next phase. Backpointer nibble = DPP
// rotation index r (prev = (tag +/- r) & 15 decoded in backtrace); ties may
// differ from jnp.argmax but path values are 0..9 << threshold. All 64 lanes
// store bp bytes (lanes n>=10 land in unused bytes 5..7 of each 8B word).
__global__ __launch_bounds__(64, 1) void crf_fused_kernel(
    const float* __restrict__ feats,
    const int*   __restrict__ lengths,
    const float* __restrict__ trans,
    float*       __restrict__ out_scores,
    float*       __restrict__ out_path,
    uint8_t*     __restrict__ bp8,
    int B, int T)
{
    __shared__ float smem[2048];    // 4 slots x 8 steps x 64 lanes

    const int lane = threadIdx.x & 63;
    const int grp  = lane >> 4;
    const int n    = lane & 15;
    const bool odd = (lane & 1);
    const int b4   = blockIdx.x * 4;
    const int b    = min(b4 + grp, B - 1);

    const int len = lengths[b];
    const int l0 = lengths[min(b4 + 0, B - 1)];
    const int l1 = lengths[min(b4 + 1, B - 1)];
    const int l2 = lengths[min(b4 + 2, B - 1)];
    const int l3 = lengths[min(b4 + 3, B - 1)];
    const int maxlen = max(max(l0, l1), max(l2, l3));
    const int len_eff = (n < TAGS) ? len : 0;   // dead lanes stay frozen

    // srcv[r] = source lane delivered by ROW_ROR:r (direction-convention-proof)
    int srcv[16];
    srcv[0]  = n;
    srcv[1]  = DPP_I(n, 0x121);  srcv[2]  = DPP_I(n, 0x122);
    srcv[3]  = DPP_I(n, 0x123);  srcv[4]  = DPP_I(n, 0x124);
    srcv[5]  = DPP_I(n, 0x125);  srcv[6]  = DPP_I(n, 0x126);
    srcv[7]  = DPP_I(n, 0x127);  srcv[8]  = DPP_I(n, 0x128);
    srcv[9]  = DPP_I(n, 0x129);  srcv[10] = DPP_I(n, 0x12A);
    srcv[11] = DPP_I(n, 0x12B);  srcv[12] = DPP_I(n, 0x12C);
    srcv[13] = DPP_I(n, 0x12D);  srcv[14] = DPP_I(n, 0x12E);
    srcv[15] = DPP_I(n, 0x12F);
    const bool dirpos = (srcv[1] == ((n + 1) & 15));  // ror delivers (n+r)&15 ?

    float trowR[16];
#pragma unroll
    for (int r = 0; r < 16; ++r) {
        const bool valid = (n < TAGS) && (srcv[r] < TAGS);
        const int  ti    = min(n, TAGS - 1) * TAGS + min(srcv[r], TAGS - 1);
        trowR[r] = valid ? trans[ti] : SENT;
    }

    float fv = (n == START_TAG) ? 0.0f : NEGV;

    const int col = (n < TAGS) ? n : 0;
    const float* fb = feats + (size_t)b * T * TAGS + col;
    uint8_t* bpb = bp8 + (size_t)b * T * 8 + (n >> 1);   // [b][t] 8B words

#define ISSUE_BLOCK(TB) {                                                     \
        const int tb_ = (TB); const int slot_ = (tb_ >> 3) & 3;               \
        _Pragma("unroll")                                                     \
        for (int i_ = 0; i_ < 8; ++i_) {                                      \
            const int tc_ = min(tb_ + i_, T - 1);                             \
            __builtin_amdgcn_global_load_lds(                                 \
                AS1C(fb + (size_t)tc_ * TAGS),                                \
                AS3(&smem[(slot_ << 9) + (i_ << 6)]), 4, 0, 0);               \
        } }

#define DS_BLOCK(TB, RN) {                                                    \
        const int slot_ = ((TB) >> 3) & 3;                                    \
        _Pragma("unroll")                                                     \
        for (int i_ = 0; i_ < 8; ++i_)                                        \
            RN[i_] = smem[(slot_ << 9) + (i_ << 6) + lane];                   \
    }

#define KLEAF(r, ctrl) {                                                      \
        int rot_ = DPP_I(__float_as_int(fv), (ctrl));                         \
        float lv_ = __int_as_float(rot_) + trowR[r];                          \
        k##r = __int_as_float((__float_as_int(lv_) & 0xFFFFFFF0) | (r)); }

#define STEPX(TI, FEAT) {                                                     \
        const int t_ = (TI);                                                  \
        float k0,k1,k2,k3,k4,k5,k6,k7,k8,k9,k10,k11,k12,k13,k14,k15;          \
        { float lv_ = fv + trowR[0];                                          \
          k0 = __int_as_float(__float_as_int(lv_) & 0xFFFFFFF0); }            \
        KLEAF(1,  0x121) KLEAF(2,  0x122) KLEAF(3,  0x123)                    \
        KLEAF(4,  0x124) KLEAF(5,  0x125) KLEAF(6,  0x126)                    \
        KLEAF(7,  0x127) KLEAF(8,  0x128) KLEAF(9,  0x129)                    \
        KLEAF(10, 0x12A) KLEAF(11, 0x12B) KLEAF(12, 0x12C)                    \
        KLEAF(13, 0x12D) KLEAF(14, 0x12E) KLEAF(15, 0x12F)                    \
        const float a1_ = maxf3(k0, k1, k2);                                  \
        const float a2_ = maxf3(k3, k4, k5);                                  \
        const float a3_ = maxf3(k6, k7, k8);                                  \
        const float a4_ = maxf3(k9, k10, k11);                                \
        const float a5_ = maxf3(k12, k13, k14);                               \
        const float mm_ = fmaxf(maxf3(a1_, a2_, a3_), maxf3(a4_, a5_, k15));  \
        const int rr_  = __float_as_int(mm_) & 15;                            \
        const int prr_ = DPP_I(rr_, 0xB1);                                    \
        const int lo_  = odd ? prr_ : rr_;                                    \
        const int hi_  = odd ? rr_ : prr_;                                    \
        const float fvn_ = mm_ + (FEAT);                                      \
        fv = (t_ < len_eff) ? fvn_ : fv;                                      \
        if (t_ < T)                                                           \
            bpb[(size_t)t_ * 8] = (uint8_t)(lo_ | (hi_ << 4));                \
    }

#define PHASE(T0, RUSE, RNEXT) {                                              \
        ISSUE_BLOCK((T0) + 24)                                                \
        asm volatile("s_waitcnt vmcnt(8)" ::: "memory");                      \
        DS_BLOCK((T0) + 8, RNEXT)                                             \
        STEPX((T0)+0, RUSE[0]) STEPX((T0)+1, RUSE[1])                         \
        STEPX((T0)+2, RUSE[2]) STEPX((T0)+3, RUSE[3])                         \
        STEPX((T0)+4, RUSE[4]) STEPX((T0)+5, RUSE[5])                         \
        STEPX((T0)+6, RUSE[6]) STEPX((T0)+7, RUSE[7])                         \
    }

    // prologue: fill slots 0..2, wait for slot 0, pull block 0 into regs
    ISSUE_BLOCK(0)
    ISSUE_BLOCK(8)
    ISSUE_BLOCK(16)
    asm volatile("s_waitcnt vmcnt(16)" ::: "memory");
    float Ra[8], Rb[8];
    DS_BLOCK(0, Ra)

    for (int t0 = 0; t0 < maxlen; t0 += 16) {
        PHASE(t0, Ra, Rb)
        PHASE(t0 + 8, Rb, Ra)
    }

    // terminal: key-packed all-reduce max within the 16-lane group
    // (exact first-index tie semantics via ^15 nibble — cheap, once)
    const float ttr  = (n < TAGS) ? trans[STOP_TAG * TAGS + n] : SENT;
    const float term = fv + ttr;
    float kk = __int_as_float((__float_as_int(term) & 0xFFFFFFF0) | (n ^ 15));
    kk = fmaxf(kk, __int_as_float(DPP_I(__float_as_int(kk), 0x128)));
    kk = fmaxf(kk, __int_as_float(DPP_I(__float_as_int(kk), 0x124)));
    kk = fmaxf(kk, __int_as_float(DPP_I(__float_as_int(kk), 0x122)));
    kk = fmaxf(kk, __int_as_float(DPP_I(__float_as_int(kk), 0x121)));
    int tag = (__float_as_int(kk) & 15) ^ 15;

    if (n == 0)
        out_scores[b] = kk;

    // drain bp stores before re-reading them
    __builtin_amdgcn_s_waitcnt(0);
    __builtin_amdgcn_sched_barrier(0);

    // fused backtrace: lane n==0 of each group walks its own contiguous row.
    // Nibble holds rotation r: prev = (tag + r) & 15 if dirpos else (tag - r) & 15.
    if (n == 0) {
        const ulonglong2* bw2 = (const ulonglong2*)(bp8 + (size_t)b * T * 8);
        float* orow = out_path + (size_t)b * T;
        const int NB = (T + 15) / 16;
        const int P2 = T / 2;                // T is even (700)
        ulonglong2 wA[8], wB[8];

        auto loadblk = [&](int bi, ulonglong2* w) {
            if (bi < 0) return;
#pragma unroll
            for (int u = 0; u < 8; ++u)
                w[u] = bw2[min(bi * 8 + u, P2 - 1)];
        };
        auto compblk = [&](int bi, ulonglong2* w) {
            float buf[16];
#pragma unroll
            for (int u = 15; u >= 0; --u) {
                int t = bi * 16 + u;
                if (t < T) {
                    uint64_t word = (u & 1) ? w[u >> 1].y : w[u >> 1].x;
                    bool act = t < len;
                    buf[u] = act ? (float)tag : 0.0f;
                    if (act) {
                        int rr = (int)((word >> (4 * tag)) & 15);
                        tag = (tag + (dirpos ? rr : 16 - rr)) & 15;
                    }
                }
            }
#pragma unroll
            for (int j = 0; j < 16; j += 4) {
                int t = bi * 16 + j;
                if (t + 3 < T)
                    *(float4*)(orow + t) = make_float4(buf[j], buf[j+1], buf[j+2], buf[j+3]);
            }
        };

        int bi = NB - 1;
        loadblk(bi, wA);
        loadblk(bi - 1, wB);
        for (; bi >= 0; bi -= 2) {
            compblk(bi, wA);
            loadblk(bi - 2, wA);
            if (bi - 1 >= 0) compblk(bi - 1, wB);
            loadblk(bi - 3, wB);
        }
    }
}

extern "C" void kernel_launch(void* const* d_in, const int* in_sizes, int n_in,
                              void* d_out, int out_size, void* d_ws, size_t ws_size,
                              hipStream_t stream)
{
    const float* feats   = (const float*)d_in[0];
    const int*   lengths = (const int*)d_in[1];
    const float* trans   = (const float*)d_in[2];
    const int B = in_sizes[1];
    const int T = in_sizes[0] / (B * TAGS);

    float* out_scores = (float*)d_out;       // [B]
    float* out_path   = (float*)d_out + B;   // [B, T] tags as floats

    uint8_t* bp8 = (uint8_t*)d_ws;           // [B][T] 8B words (5 bytes used)

    crf_fused_kernel<<<(B + 3) / 4, 64, 0, stream>>>(
        feats, lengths, trans, out_scores, out_path, bp8, B, T);
}

// Round 8
// 135.370 us; speedup vs baseline: 1.2999x; 1.2999x over previous
//
#include <hip/hip_runtime.h>
#include <stdint.h>

#define TAGS 10
#define START_TAG 8
#define STOP_TAG 9
#define NEGV (-10000.0f)

// DPP within 16-lane rows. ROW_ROR:r = 0x120+r, QUAD_PERM[1,0,3,2] = 0xB1.
#define DPP_I(x, ctrl) __builtin_amdgcn_update_dpp(0, (x), (ctrl), 0xF, 0xF, true)

__device__ __forceinline__ float maxf3(float a, float b, float c) {
    return fmaxf(fmaxf(a, b), c);   // folds to v_max3_f32
}

// Fused Viterbi forward + backtrace, 8-tag reduction (exact: START/STOP can
// never win an argmax for t>=1 or the terminal — blocked by -1e4 transitions;
// t=0 is closed-form fv[n] = trans[n][START] + feat0[n], and bp[0] is never
// read). 16 lanes/seq with tags 0..7 DUPLICATED in both octets, so row_ror:r
// (r=1..7) delivers every prev tag: 7 DPPs + 8 adds + 8 packs + 4-op max3
// tree per step. Argmax carried in the low 3 mantissa bits (prev^7 => ties
// pick the smallest prev, jnp.argmax semantics, <=8ulp value perturbation).
// Backpointers: 8 nibbles = 4 B per (b,t) at bp[b][t]; fused backtrace reads
// its own contiguous row as uint4s.
__global__ __launch_bounds__(64, 1) void crf_fused_kernel(
    const float* __restrict__ feats,
    const int*   __restrict__ lengths,
    const float* __restrict__ trans,
    float*       __restrict__ out_scores,
    float*       __restrict__ out_path,
    uint8_t*     __restrict__ bp4,
    int B, int T)
{
    const int lane = threadIdx.x & 63;
    const int grp  = lane >> 4;
    const int n    = lane & 15;       // position in 16-row (two octets)
    const int m    = n & 7;           // tag owned by this lane
    const bool odd = (n & 1);
    const int b4   = blockIdx.x * 4;
    const int b    = min(b4 + grp, B - 1);

    const int len = lengths[b];
    const int l0 = lengths[min(b4 + 0, B - 1)];
    const int l1 = lengths[min(b4 + 1, B - 1)];
    const int l2 = lengths[min(b4 + 2, B - 1)];
    const int l3 = lengths[min(b4 + 3, B - 1)];
    const int maxlen = max(max(l0, l1), max(l2, l3));

    // srcv[r] = source lane for ROW_ROR:r (direction-convention-proof);
    // source TAG = srcv[r] & 7 thanks to octet duplication.
    int srcv[8];
    srcv[0] = n;
    srcv[1] = DPP_I(n, 0x121);  srcv[2] = DPP_I(n, 0x122);
    srcv[3] = DPP_I(n, 0x123);  srcv[4] = DPP_I(n, 0x124);
    srcv[5] = DPP_I(n, 0x125);  srcv[6] = DPP_I(n, 0x126);
    srcv[7] = DPP_I(n, 0x127);

    float trowR[8];
    int   rsrc[8];
#pragma unroll
    for (int r = 0; r < 8; ++r) {
        const int s = srcv[r] & 7;
        trowR[r] = trans[m * TAGS + s];
        rsrc[r]  = s ^ 7;            // larger key nibble => smaller prev index
    }

    const float* fb = feats + (size_t)b * T * TAGS + m;
    uint8_t* bpb = bp4 + (size_t)b * T * 4 + (n >> 1);
    const bool store_lane = (n < 8) && !odd;     // lanes 0,2,4,6 -> bytes 0..3

    // t = 0 closed form (len >= 1 always): fv[m] = trans[m][START] + feat0[m]
    float fv = trans[m * TAGS + START_TAG] + fb[0];

#define KLEAF(r, ctrl) {                                                      \
        int rot_ = DPP_I(__float_as_int(fv), (ctrl));                         \
        float lv_ = __int_as_float(rot_) + trowR[r];                          \
        k##r = __int_as_float((__float_as_int(lv_) & ~7) | rsrc[r]); }

#define STEPX(TI, FEAT) {                                                     \
        const int t_ = (TI);                                                  \
        float k0, k1, k2, k3, k4, k5, k6, k7;                                 \
        { float lv_ = fv + trowR[0];                                          \
          k0 = __int_as_float((__float_as_int(lv_) & ~7) | rsrc[0]); }        \
        KLEAF(1, 0x121) KLEAF(2, 0x122) KLEAF(3, 0x123)                       \
        KLEAF(4, 0x124) KLEAF(5, 0x125) KLEAF(6, 0x126)                       \
        KLEAF(7, 0x127)                                                       \
        const float p1_ = maxf3(k0, k1, k2);                                  \
        const float p2_ = maxf3(k3, k4, k5);                                  \
        const float p3_ = maxf3(k6, k7, p1_);                                 \
        const float mm_ = fmaxf(p2_, p3_);                                    \
        const int   idx_  = (__float_as_int(mm_) & 7) ^ 7;   /* true prev */  \
        const int   pidx_ = DPP_I(idx_, 0xB1);               /* lane^1 */     \
        const int   lo_   = odd ? pidx_ : idx_;                               \
        const int   hi_   = odd ? idx_ : pidx_;                               \
        const float fvn_  = mm_ + (FEAT);                                     \
        fv = (t_ < len) ? fvn_ : fv;                                          \
        if (t_ < T) {                                                         \
            if (store_lane)                                                   \
                bpb[(size_t)t_ * 4] = (uint8_t)(lo_ | (hi_ << 4));            \
        } }

    float fc[8], fn[8];
#pragma unroll
    for (int i = 0; i < 8; ++i)
        fc[i] = fb[(size_t)min(1 + i, T - 1) * TAGS];

    for (int t0 = 1; t0 < maxlen; t0 += 8) {
#pragma unroll
        for (int i = 0; i < 8; ++i)
            fn[i] = fb[(size_t)min(t0 + 8 + i, T - 1) * TAGS];

        STEPX(t0 + 0, fc[0]) STEPX(t0 + 1, fc[1])
        STEPX(t0 + 2, fc[2]) STEPX(t0 + 3, fc[3])
        STEPX(t0 + 4, fc[4]) STEPX(t0 + 5, fc[5])
        STEPX(t0 + 6, fc[6]) STEPX(t0 + 7, fc[7])

#pragma unroll
        for (int i = 0; i < 8; ++i) fc[i] = fn[i];
    }
#undef KLEAF
#undef STEPX

    // terminal over tags 0..7 (exact: 8/9 can't win). 3 DPP-reduce rounds:
    // any 8 consecutive lanes of the duplicated row cover all 8 tags.
    const float term = fv + trans[STOP_TAG * TAGS + m];
    float kk = __int_as_float((__float_as_int(term) & ~7) | (m ^ 7));
    kk = fmaxf(kk, __int_as_float(DPP_I(__float_as_int(kk), 0x124)));  // ror 4
    kk = fmaxf(kk, __int_as_float(DPP_I(__float_as_int(kk), 0x122)));  // ror 2
    kk = fmaxf(kk, __int_as_float(DPP_I(__float_as_int(kk), 0x121)));  // ror 1
    int tag = (__float_as_int(kk) & 7) ^ 7;

    if (n == 0)
        out_scores[b] = kk;

    // drain bp stores before re-reading them
    __builtin_amdgcn_s_waitcnt(0);
    __builtin_amdgcn_sched_barrier(0);

    // fused backtrace: lane n==0 of each group walks its own contiguous row.
    // bp word (4B) for step t: nibble 4*tag = true prev tag.
    if (n == 0) {
        const uint32_t* rw = (const uint32_t*)(bp4 + (size_t)b * T * 4);
        float* orow = out_path + (size_t)b * T;
        const int NB = (T + 15) / 16;
        uint32_t wA[16], wB[16];

        auto loadblk = [&](int bi, uint32_t* w) {
            if (bi < 0) return;
#pragma unroll
            for (int j = 0; j < 4; ++j) {
                const int tb = min(bi * 16 + 4 * j, T - 4);   // T%4==0, aligned
                *(uint4*)&w[4 * j] = *(const uint4*)&rw[tb];
            }
        };
        auto compblk = [&](int bi, uint32_t* w) {
            float buf[16];
#pragma unroll
            for (int u = 15; u >= 0; --u) {
                const int t = bi * 16 + u;
                if (t < T) {
                    const bool act = t < len;
                    buf[u] = act ? (float)tag : 0.0f;   // path[t]; 0 past len
                    if (act) tag = (int)((w[u] >> (4 * tag)) & 15);
                }
            }
#pragma unroll
            for (int j = 0; j < 16; j += 4) {
                const int t = bi * 16 + j;
                if (t + 3 < T)
                    *(float4*)(orow + t) = make_float4(buf[j], buf[j+1], buf[j+2], buf[j+3]);
            }
        };

        int bi = NB - 1;
        loadblk(bi, wA);
        loadblk(bi - 1, wB);
        for (; bi >= 0; bi -= 2) {
            compblk(bi, wA);
            loadblk(bi - 2, wA);
            if (bi - 1 >= 0) compblk(bi - 1, wB);
            loadblk(bi - 3, wB);
        }
    }
}

extern "C" void kernel_launch(void* const* d_in, const int* in_sizes, int n_in,
                              void* d_out, int out_size, void* d_ws, size_t ws_size,
                              hipStream_t stream)
{
    const float* feats   = (const float*)d_in[0];
    const int*   lengths = (const int*)d_in[1];
    const float* trans   = (const float*)d_in[2];
    const int B = in_sizes[1];
    const int T = in_sizes[0] / (B * TAGS);

    float* out_scores = (float*)d_out;       // [B]
    float* out_path   = (float*)d_out + B;   // [B, T] tags as floats

    uint8_t* bp4 = (uint8_t*)d_ws;           // [B][T] 4B words

    crf_fused_kernel<<<(B + 3) / 4, 64, 0, stream>>>(
        feats, lengths, trans, out_scores, out_path, bp4, B, T);
}

// Round 9
// 117.928 us; speedup vs baseline: 1.4921x; 1.1479x over previous
//
#include <hip/hip_runtime.h>
#include <stdint.h>

#define TAGS 10
#define START_TAG 8
#define STOP_TAG 9
#define NEGV (-10000.0f)
#define BIGNEG (-1.0e9f)

// DPP within 16-lane rows: ROW_ROR:r = 0x120+r, QUAD_PERM[1,0,3,2] = 0xB1.
#define DPP_I(x, ctrl) __builtin_amdgcn_update_dpp(0, (x), (ctrl), 0xF, 0xF, true)
// ds_swizzle BitMode XOR-r within 32-lane halves: offset = (r<<10) | and_mask 0x1F.
#define SWZ_I(x, r) __builtin_amdgcn_ds_swizzle((x), (((r) << 10) | 0x1F))

__device__ __forceinline__ float maxf3(float a, float b, float c) {
    return fmaxf(fmaxf(a, b), c);   // folds to v_max3_f32
}

// ===========================================================================
// K1: split forward. Blocks [0,ABLK): half-A = true Viterbi t in [0,H)
// (8-tag duplicated-octet layout, 4 seqs/wave, exactly the R8 kernel bounded
// at H; writes bpA[b][t] 4B nibble words + fvA[b][8] = fv at t=H-1).
// Blocks [ABLK, ABLK+B): half-B = 8 basis recurrences for ONE sequence,
// t in [H, len): 64 lanes = 8 basis octets x 8 tags; gathers via ds_swizzle
// XOR r (in-octet); writes bpB[s][t-H][basis] 4B words + g[s][64].
// Seqs with len <= H exit immediately (half-B contributes nothing).
// ===========================================================================
__global__ __launch_bounds__(64, 1) void crf_split_fwd(
    const float* __restrict__ feats,
    const int*   __restrict__ lengths,
    const float* __restrict__ trans,
    uint8_t*     __restrict__ bpA,
    uint8_t*     __restrict__ bpB,
    float*       __restrict__ fvAo,
    float*       __restrict__ gws,
    int B, int T, int H, int ABLK)
{
    const int lane = threadIdx.x & 63;

    if ((int)blockIdx.x < ABLK) {
        // ---------------- half A ----------------
        const int grp  = lane >> 4;
        const int n    = lane & 15;
        const int m    = n & 7;
        const bool odd = (n & 1);
        const int b4   = blockIdx.x * 4;
        const int b    = min(b4 + grp, B - 1);

        const int len  = lengths[b];
        const int lenA = min(len, H);      // freeze at seam: fv must be fv_{H-1}
        const int l0 = lengths[min(b4 + 0, B - 1)];
        const int l1 = lengths[min(b4 + 1, B - 1)];
        const int l2 = lengths[min(b4 + 2, B - 1)];
        const int l3 = lengths[min(b4 + 3, B - 1)];
        const int HA = min(max(max(l0, l1), max(l2, l3)), H);

        int srcv[8];
        srcv[0] = n;
        srcv[1] = DPP_I(n, 0x121);  srcv[2] = DPP_I(n, 0x122);
        srcv[3] = DPP_I(n, 0x123);  srcv[4] = DPP_I(n, 0x124);
        srcv[5] = DPP_I(n, 0x125);  srcv[6] = DPP_I(n, 0x126);
        srcv[7] = DPP_I(n, 0x127);

        float trowR[8];
        int   rsrc[8];
#pragma unroll
        for (int r = 0; r < 8; ++r) {
            const int sq = srcv[r] & 7;
            trowR[r] = trans[m * TAGS + sq];
            rsrc[r]  = sq ^ 7;
        }

        const float* fb = feats + (size_t)b * T * TAGS + m;
        uint8_t* bpb = bpA + (size_t)b * H * 4 + (n >> 1);
        const bool stl = (n < 8) && !odd;

        float fv = trans[m * TAGS + START_TAG] + fb[0];   // t=0 closed form

#define KLEAF_A(r, ctrl) {                                                    \
        int rot_ = DPP_I(__float_as_int(fv), (ctrl));                         \
        float lv_ = __int_as_float(rot_) + trowR[r];                          \
        k##r = __int_as_float((__float_as_int(lv_) & ~7) | rsrc[r]); }

#define STEP_A(TI, FEAT) {                                                    \
        const int t_ = (TI);                                                  \
        float k0, k1, k2, k3, k4, k5, k6, k7;                                 \
        { float lv_ = fv + trowR[0];                                          \
          k0 = __int_as_float((__float_as_int(lv_) & ~7) | rsrc[0]); }        \
        KLEAF_A(1, 0x121) KLEAF_A(2, 0x122) KLEAF_A(3, 0x123)                 \
        KLEAF_A(4, 0x124) KLEAF_A(5, 0x125) KLEAF_A(6, 0x126)                 \
        KLEAF_A(7, 0x127)                                                     \
        const float p1_ = maxf3(k0, k1, k2);                                  \
        const float p2_ = maxf3(k3, k4, k5);                                  \
        const float p3_ = maxf3(k6, k7, p1_);                                 \
        const float mm_ = fmaxf(p2_, p3_);                                    \
        const int   idx_  = (__float_as_int(mm_) & 7) ^ 7;                    \
        const int   pidx_ = DPP_I(idx_, 0xB1);                                \
        const int   lo_   = odd ? pidx_ : idx_;                               \
        const int   hi_   = odd ? idx_ : pidx_;                               \
        const float fvn_  = mm_ + (FEAT);                                     \
        fv = (t_ < lenA) ? fvn_ : fv;                                         \
        if (t_ < H) {                                                         \
            if (stl) bpb[(size_t)t_ * 4] = (uint8_t)(lo_ | (hi_ << 4));       \
        } }

        float fc[8], fn[8];
#pragma unroll
        for (int i = 0; i < 8; ++i)
            fc[i] = fb[(size_t)min(1 + i, T - 1) * TAGS];

        for (int t0 = 1; t0 < HA; t0 += 8) {
#pragma unroll
            for (int i = 0; i < 8; ++i)
                fn[i] = fb[(size_t)min(t0 + 8 + i, T - 1) * TAGS];

            STEP_A(t0 + 0, fc[0]) STEP_A(t0 + 1, fc[1])
            STEP_A(t0 + 2, fc[2]) STEP_A(t0 + 3, fc[3])
            STEP_A(t0 + 4, fc[4]) STEP_A(t0 + 5, fc[5])
            STEP_A(t0 + 6, fc[6]) STEP_A(t0 + 7, fc[7])

#pragma unroll
            for (int i = 0; i < 8; ++i) fc[i] = fn[i];
        }
#undef KLEAF_A
#undef STEP_A

        if (n < 8)
            fvAo[(size_t)b * 8 + m] = fv;
    } else {
        // ---------------- half B ----------------
        const int s = blockIdx.x - ABLK;
        if (s >= B) return;
        const int len = lengths[s];
        if (len <= H) return;

        const int p    = lane >> 3;       // basis octet
        const int n    = lane & 7;        // tag
        const bool odd = (n & 1);
        const int TB   = T - H;

        float trowR[8];
        int   rsrc[8];
#pragma unroll
        for (int r = 0; r < 8; ++r) {
            const int q = n ^ r;          // swizzle xor-r source tag
            trowR[r] = trans[n * TAGS + q];
            rsrc[r]  = q ^ 7;
        }

        float g = (n == p) ? 0.0f : BIGNEG;   // basis e_p at t = H-1

        const float* fb = feats + (size_t)s * T * TAGS + n;
        uint8_t* bpb = bpB + (size_t)s * TB * 32 + p * 4 + (n >> 1);

#define KLEAF_B(r) {                                                          \
        int rot_ = SWZ_I(__float_as_int(g), r);                               \
        float lv_ = __int_as_float(rot_) + trowR[r];                          \
        k##r = __int_as_float((__float_as_int(lv_) & ~7) | rsrc[r]); }

#define STEP_B(TI, FEAT) {                                                    \
        const int t_ = (TI);                                                  \
        float k0, k1, k2, k3, k4, k5, k6, k7;                                 \
        { float lv_ = g + trowR[0];                                           \
          k0 = __int_as_float((__float_as_int(lv_) & ~7) | rsrc[0]); }        \
        KLEAF_B(1) KLEAF_B(2) KLEAF_B(3)                                      \
        KLEAF_B(4) KLEAF_B(5) KLEAF_B(6) KLEAF_B(7)                           \
        const float p1_ = maxf3(k0, k1, k2);                                  \
        const float p2_ = maxf3(k3, k4, k5);                                  \
        const float p3_ = maxf3(k6, k7, p1_);                                 \
        const float mm_ = fmaxf(p2_, p3_);                                    \
        if (t_ < len) {   /* uniform: len is wave-uniform (1 seq/wave) */     \
            const int idx_ = (__float_as_int(mm_) & 7) ^ 7;                   \
            const int pp_  = SWZ_I(idx_, 1);                                  \
            if (!odd) bpb[(size_t)(t_ - H) * 32] = (uint8_t)(idx_ | (pp_ << 4)); \
            g = mm_ + (FEAT);                                                 \
        } }

        float fc[8], fn[8];
#pragma unroll
        for (int i = 0; i < 8; ++i)
            fc[i] = fb[(size_t)min(H + i, len - 1) * TAGS];

        for (int t0 = H; t0 < len; t0 += 8) {
#pragma unroll
            for (int i = 0; i < 8; ++i)
                fn[i] = fb[(size_t)min(t0 + 8 + i, len - 1) * TAGS];

            STEP_B(t0 + 0, fc[0]) STEP_B(t0 + 1, fc[1])
            STEP_B(t0 + 2, fc[2]) STEP_B(t0 + 3, fc[3])
            STEP_B(t0 + 4, fc[4]) STEP_B(t0 + 5, fc[5])
            STEP_B(t0 + 6, fc[6]) STEP_B(t0 + 7, fc[7])

#pragma unroll
            for (int i = 0; i < 8; ++i) fc[i] = fn[i];
        }
#undef KLEAF_B
#undef STEP_B

        gws[(size_t)s * 64 + lane] = g;   // lane = p*8 + n
    }
}

// ===========================================================================
// K2: seam + terminal + two independent backtrace walks per sequence.
// Blocks [0,rb): role B (writes score + path[H..T)); blocks [rb,2rb): role A
// (path[0..H)). Both recompute the cheap seam: fv[n] = max_p fvA[p]+g[p][n]
// (len>H) else fvA; terminal over tags 0..7 (START/STOP blocked by -1e4);
// p* = argmax_p for the winning tag = state at H-1 = A-walk start tag.
// ===========================================================================
__global__ __launch_bounds__(64, 1) void crf_split_bt(
    const int*     __restrict__ lengths,
    const float*   __restrict__ trans,
    const uint8_t* __restrict__ bpA,
    const uint8_t* __restrict__ bpB,
    const float*   __restrict__ fvA,
    const float*   __restrict__ gws,
    float*         __restrict__ out_scores,
    float*         __restrict__ out_path,
    int B, int T, int H)
{
    const int rb = (B + 63) >> 6;
    const bool roleB = ((int)blockIdx.x < rb);
    const int s = (roleB ? (int)blockIdx.x : (int)blockIdx.x - rb) * 64 + threadIdx.x;
    if (s >= B) return;
    const int len = lengths[s];
    const int TB  = T - H;

    float fa[8];
    {
        const float4* f4 = (const float4*)(fvA + (size_t)s * 8);
        float4 a = f4[0], c = f4[1];
        fa[0]=a.x; fa[1]=a.y; fa[2]=a.z; fa[3]=a.w;
        fa[4]=c.x; fa[5]=c.y; fa[6]=c.z; fa[7]=c.w;
    }
    const float* gr = gws + (size_t)s * 64;
    float fv[8];
    if (len > H) {
#pragma unroll
        for (int nn = 0; nn < 8; ++nn) fv[nn] = fa[0] + gr[nn];
#pragma unroll
        for (int pp = 1; pp < 8; ++pp)
#pragma unroll
            for (int nn = 0; nn < 8; ++nn)
                fv[nn] = fmaxf(fv[nn], fa[pp] + gr[pp * 8 + nn]);
    } else {
#pragma unroll
        for (int nn = 0; nn < 8; ++nn) fv[nn] = fa[nn];
    }

    float best = fv[0] + trans[STOP_TAG * TAGS + 0];
    int ltag = 0;
#pragma unroll
    for (int nn = 1; nn < 8; ++nn) {
        const float tv = fv[nn] + trans[STOP_TAG * TAGS + nn];
        if (tv > best) { best = tv; ltag = nn; }
    }
    int pstar = 0;
    if (len > H) {
        float bb = fa[0] + gr[ltag];
#pragma unroll
        for (int pp = 1; pp < 8; ++pp) {
            const float v = fa[pp] + gr[pp * 8 + ltag];
            if (v > bb) { bb = v; pstar = pp; }
        }
    }

    float* orow = out_path + (size_t)s * T;

    if (roleB) {
        out_scores[s] = best;
        int tag = ltag;
        const uint8_t* bb8 = bpB + (size_t)s * TB * 32 + pstar * 4;
        const int bi_lo = H >> 4;          // H is a multiple of 16
        const int bi_hi = (T - 1) >> 4;
        uint32_t w0[16], w1[16];

        auto loadB = [&](int bi, uint32_t* w) {
            if (bi < bi_lo) return;
#pragma unroll
            for (int u = 0; u < 16; ++u) {
                const int tc = min(bi * 16 + u, T - 1);
                w[u] = *(const uint32_t*)(bb8 + (size_t)(tc - H) * 32);
            }
        };
        auto compB = [&](int bi, uint32_t* w) {
            float buf[16];
#pragma unroll
            for (int u = 15; u >= 0; --u) {
                const int t = bi * 16 + u;
                if (t < T) {
                    const bool act = t < len;
                    buf[u] = act ? (float)tag : 0.0f;
                    if (act) tag = (int)((w[u] >> (4 * tag)) & 7);
                }
            }
#pragma unroll
            for (int j = 0; j < 16; j += 4) {
                const int t = bi * 16 + j;
                if (t + 3 < T)
                    *(float4*)(orow + t) = make_float4(buf[j], buf[j+1], buf[j+2], buf[j+3]);
            }
        };

        int bi = bi_hi;
        loadB(bi, w0); loadB(bi - 1, w1);
        for (; bi >= bi_lo; bi -= 2) {
            compB(bi, w0); loadB(bi - 2, w0);
            if (bi - 1 >= bi_lo) compB(bi - 1, w1);
            loadB(bi - 3, w1);
        }
    } else {
        const int lenA2 = min(len, H);
        int tag = (len > H) ? pstar : ltag;
        const uint32_t* wa = (const uint32_t*)(bpA + (size_t)s * H * 4);
        const int NB = H >> 4;
        uint32_t w0[16], w1[16];

        auto loadA = [&](int bi, uint32_t* w) {
            if (bi < 0) return;
#pragma unroll
            for (int j = 0; j < 4; ++j)
                *(uint4*)&w[4 * j] = *(const uint4*)&wa[bi * 16 + 4 * j];
        };
        auto compA = [&](int bi, uint32_t* w) {
            float buf[16];
#pragma unroll
            for (int u = 15; u >= 0; --u) {
                const int t = bi * 16 + u;
                const bool act = t < lenA2;
                buf[u] = act ? (float)tag : 0.0f;
                if (act && t > 0) tag = (int)((w[u] >> (4 * tag)) & 7);
            }
#pragma unroll
            for (int j = 0; j < 16; j += 4)
                *(float4*)(orow + bi * 16 + j) = make_float4(buf[j], buf[j+1], buf[j+2], buf[j+3]);
        };

        int bi = NB - 1;
        loadA(bi, w0); loadA(bi - 1, w1);
        for (; bi >= 0; bi -= 2) {
            compA(bi, w0); loadA(bi - 2, w0);
            if (bi - 1 >= 0) compA(bi - 1, w1);
            loadA(bi - 3, w1);
        }
    }
}

// ===========================================================================
// Fallback: R9-verbatim copy of the R8 fused kernel (used if ws too small).
// ===========================================================================
__global__ __launch_bounds__(64, 1) void crf_fused_small(
    const float* __restrict__ feats,
    const int*   __restrict__ lengths,
    const float* __restrict__ trans,
    float*       __restrict__ out_scores,
    float*       __restrict__ out_path,
    uint8_t*     __restrict__ bp4,
    int B, int T)
{
    const int lane = threadIdx.x & 63;
    const int grp  = lane >> 4;
    const int n    = lane & 15;
    const int m    = n & 7;
    const bool odd = (n & 1);
    const int b4   = blockIdx.x * 4;
    const int b    = min(b4 + grp, B - 1);

    const int len = lengths[b];
    const int l0 = lengths[min(b4 + 0, B - 1)];
    const int l1 = lengths[min(b4 + 1, B - 1)];
    const int l2 = lengths[min(b4 + 2, B - 1)];
    const int l3 = lengths[min(b4 + 3, B - 1)];
    const int maxlen = max(max(l0, l1), max(l2, l3));

    int srcv[8];
    srcv[0] = n;
    srcv[1] = DPP_I(n, 0x121);  srcv[2] = DPP_I(n, 0x122);
    srcv[3] = DPP_I(n, 0x123);  srcv[4] = DPP_I(n, 0x124);
    srcv[5] = DPP_I(n, 0x125);  srcv[6] = DPP_I(n, 0x126);
    srcv[7] = DPP_I(n, 0x127);

    float trowR[8];
    int   rsrc[8];
#pragma unroll
    for (int r = 0; r < 8; ++r) {
        const int sq = srcv[r] & 7;
        trowR[r] = trans[m * TAGS + sq];
        rsrc[r]  = sq ^ 7;
    }

    const float* fb = feats + (size_t)b * T * TAGS + m;
    uint8_t* bpb = bp4 + (size_t)b * T * 4 + (n >> 1);
    const bool store_lane = (n < 8) && !odd;

    float fv = trans[m * TAGS + START_TAG] + fb[0];

#define KLEAF_S(r, ctrl) {                                                    \
        int rot_ = DPP_I(__float_as_int(fv), (ctrl));                         \
        float lv_ = __int_as_float(rot_) + trowR[r];                          \
        k##r = __int_as_float((__float_as_int(lv_) & ~7) | rsrc[r]); }

#define STEP_S(TI, FEAT) {                                                    \
        const int t_ = (TI);                                                  \
        float k0, k1, k2, k3, k4, k5, k6, k7;                                 \
        { float lv_ = fv + trowR[0];                                          \
          k0 = __int_as_float((__float_as_int(lv_) & ~7) | rsrc[0]); }        \
        KLEAF_S(1, 0x121) KLEAF_S(2, 0x122) KLEAF_S(3, 0x123)                 \
        KLEAF_S(4, 0x124) KLEAF_S(5, 0x125) KLEAF_S(6, 0x126)                 \
        KLEAF_S(7, 0x127)                                                     \
        const float p1_ = maxf3(k0, k1, k2);                                  \
        const float p2_ = maxf3(k3, k4, k5);                                  \
        const float p3_ = maxf3(k6, k7, p1_);                                 \
        const float mm_ = fmaxf(p2_, p3_);                                    \
        const int   idx_  = (__float_as_int(mm_) & 7) ^ 7;                    \
        const int   pidx_ = DPP_I(idx_, 0xB1);                                \
        const int   lo_   = odd ? pidx_ : idx_;                               \
        const int   hi_   = odd ? idx_ : pidx_;                               \
        const float fvn_  = mm_ + (FEAT);                                     \
        fv = (t_ < len) ? fvn_ : fv;                                          \
        if (t_ < T) {                                                         \
            if (store_lane)                                                   \
                bpb[(size_t)t_ * 4] = (uint8_t)(lo_ | (hi_ << 4));            \
        } }

    float fc[8], fn[8];
#pragma unroll
    for (int i = 0; i < 8; ++i)
        fc[i] = fb[(size_t)min(1 + i, T - 1) * TAGS];

    for (int t0 = 1; t0 < maxlen; t0 += 8) {
#pragma unroll
        for (int i = 0; i < 8; ++i)
            fn[i] = fb[(size_t)min(t0 + 8 + i, T - 1) * TAGS];

        STEP_S(t0 + 0, fc[0]) STEP_S(t0 + 1, fc[1])
        STEP_S(t0 + 2, fc[2]) STEP_S(t0 + 3, fc[3])
        STEP_S(t0 + 4, fc[4]) STEP_S(t0 + 5, fc[5])
        STEP_S(t0 + 6, fc[6]) STEP_S(t0 + 7, fc[7])

#pragma unroll
        for (int i = 0; i < 8; ++i) fc[i] = fn[i];
    }
#undef KLEAF_S
#undef STEP_S

    const float term = fv + trans[STOP_TAG * TAGS + m];
    float kk = __int_as_float((__float_as_int(term) & ~7) | (m ^ 7));
    kk = fmaxf(kk, __int_as_float(DPP_I(__float_as_int(kk), 0x124)));
    kk = fmaxf(kk, __int_as_float(DPP_I(__float_as_int(kk), 0x122)));
    kk = fmaxf(kk, __int_as_float(DPP_I(__float_as_int(kk), 0x121)));
    int tag = (__float_as_int(kk) & 7) ^ 7;

    if (n == 0)
        out_scores[b] = kk;

    __builtin_amdgcn_s_waitcnt(0);
    __builtin_amdgcn_sched_barrier(0);

    if (n == 0) {
        const uint32_t* rw = (const uint32_t*)(bp4 + (size_t)b * T * 4);
        float* orow = out_path + (size_t)b * T;
        const int NB = (T + 15) / 16;
        uint32_t wA[16], wB[16];

        auto loadblk = [&](int bi, uint32_t* w) {
            if (bi < 0) return;
#pragma unroll
            for (int j = 0; j < 4; ++j) {
                const int tb = min(bi * 16 + 4 * j, T - 4);
                *(uint4*)&w[4 * j] = *(const uint4*)&rw[tb];
            }
        };
        auto compblk = [&](int bi, uint32_t* w) {
            float buf[16];
#pragma unroll
            for (int u = 15; u >= 0; --u) {
                const int t = bi * 16 + u;
                if (t < T) {
                    const bool act = t < len;
                    buf[u] = act ? (float)tag : 0.0f;
                    if (act) tag = (int)((w[u] >> (4 * tag)) & 15);
                }
            }
#pragma unroll
            for (int j = 0; j < 16; j += 4) {
                const int t = bi * 16 + j;
                if (t + 3 < T)
                    *(float4*)(orow + t) = make_float4(buf[j], buf[j+1], buf[j+2], buf[j+3]);
            }
        };

        int bi = NB - 1;
        loadblk(bi, wA);
        loadblk(bi - 1, wB);
        for (; bi >= 0; bi -= 2) {
            compblk(bi, wA);
            loadblk(bi - 2, wA);
            if (bi - 1 >= 0) compblk(bi - 1, wB);
            loadblk(bi - 3, wB);
        }
    }
}

extern "C" void kernel_launch(void* const* d_in, const int* in_sizes, int n_in,
                              void* d_out, int out_size, void* d_ws, size_t ws_size,
                              hipStream_t stream)
{
    const float* feats   = (const float*)d_in[0];
    const int*   lengths = (const int*)d_in[1];
    const float* trans   = (const float*)d_in[2];
    const int B = in_sizes[1];
    const int T = in_sizes[0] / (B * TAGS);

    float* out_scores = (float*)d_out;       // [B]
    float* out_path   = (float*)d_out + B;   // [B, T] tags as floats

    int H = ((T / 2) + 15) & ~15;            // seam, multiple of 16
    const int TB = T - H;

    size_t szA = (size_t)B * H * 4;
    size_t szB = (size_t)B * TB * 32;
    size_t szF = (size_t)B * 8 * 4;
    size_t szG = (size_t)B * 64 * 4;
    size_t need = szA + szB + szF + szG;

    if (H >= 16 && H < T && (T & 3) == 0 && ws_size >= need) {
        uint8_t* bpA  = (uint8_t*)d_ws;
        uint8_t* bpB  = bpA + szA;
        float*   fvAo = (float*)(bpB + szB);
        float*   gws  = (float*)((uint8_t*)fvAo + szF);
        const int ABLK = (B + 3) / 4;

        crf_split_fwd<<<ABLK + B, 64, 0, stream>>>(
            feats, lengths, trans, bpA, bpB, fvAo, gws, B, T, H, ABLK);

        const int rb = (B + 63) >> 6;
        crf_split_bt<<<2 * rb, 64, 0, stream>>>(
            lengths, trans, bpA, bpB, fvAo, gws, out_scores, out_path, B, T, H);
    } else {
        uint8_t* bp4 = (uint8_t*)d_ws;       // [B][T] 4B words
        crf_fused_small<<<(B + 3) / 4, 64, 0, stream>>>(
            feats, lengths, trans, out_scores, out_path, bp4, B, T);
    }
}